// Round 3
// baseline (965.332 us; speedup 1.0000x reference)
//
#include <hip/hip_runtime.h>
#include <math.h>

#define TSTEPS 288
#define NTHREADS 1024

__device__ __forceinline__ float sigmoidf_(float x) {
    return 1.0f / (1.0f + __expf(-x));
}

// Butterfly all-reduce over the low log2(NS) lane bits.
// xor1/xor2 via DPP quad_perm (VALU pipe); xor4/8/16 via ds_swizzle.
// All lanes end with the identical (bitwise) total: fp add is commutative,
// and each butterfly stage pairs identical operand sets.
template<int NS>
__device__ __forceinline__ float allreduce_seg(float v) {
    if constexpr (NS > 1)
        v += __int_as_float(__builtin_amdgcn_update_dpp(
                0, __float_as_int(v), 0xB1, 0xF, 0xF, true));   // xor 1
    if constexpr (NS > 2)
        v += __int_as_float(__builtin_amdgcn_update_dpp(
                0, __float_as_int(v), 0x4E, 0xF, 0xF, true));   // xor 2
    if constexpr (NS > 4)
        v += __int_as_float(__builtin_amdgcn_ds_swizzle(__float_as_int(v), 0x101F)); // xor 4
    if constexpr (NS > 8)
        v += __int_as_float(__builtin_amdgcn_ds_swizzle(__float_as_int(v), 0x201F)); // xor 8
    if constexpr (NS > 16)
        v += __int_as_float(__builtin_amdgcn_ds_swizzle(__float_as_int(v), 0x401F)); // xor 16
    return v;
}

// One block = one sample. Thread (u, seg): u = tid>>S owns unit u's 4 gate
// columns {u, U+u, 2U+u, 3U+u}; seg = tid & (NS-1) covers KIN input rows and
// KH hidden rows. seg lives in the LOW lane bits so the cross-seg reduction
// is an in-wave butterfly; afterwards every lane has the unit's 4 gate sums
// and computes the gate update redundantly (c state kept per-lane, identical).
// One barrier per timestep; xh is ping-pong double-buffered.
// WRITE_NOW: write h to seq[t] in-region (layer reads no seq -> safe).
// WRITE_DELAY: write h of step t-1 to seq[t-1] during region t (WAR-safe).
template<int DIN, int U, bool FIRST, bool WRITE_NOW, bool WRITE_DELAY>
__device__ void run_layer(const float* __restrict__ Wk,
                          const float* __restrict__ Wr,
                          const float* __restrict__ bias,
                          const float* __restrict__ xg,   // x + b*T*64 (FIRST only)
                          float* __restrict__ seq,
                          float* __restrict__ xh,         // 2 x 128 ping-pong
                          int tid)
{
    constexpr int NS   = NTHREADS / U;                    // k-split factor
    constexpr int S    = (NS == 8) ? 3 : (NS == 16) ? 4 : 5;
    constexpr int KIN  = DIN / NS;
    constexpr int KH   = U / NS;
    constexpr int COLS = 4 * U;
    static_assert(NS <= 32, "butterfly must fit in 32-lane swizzle groups");

    const int seg = tid & (NS - 1);
    const int u   = tid >> S;

    // ---- register-resident weights: 4 gate columns x (KIN+KH) rows ----
    float w[4][KIN + KH];
#pragma unroll
    for (int k = 0; k < KIN; ++k) {
        const float* row = Wk + (size_t)(seg * KIN + k) * COLS + u;
#pragma unroll
        for (int g = 0; g < 4; ++g) w[g][k] = row[g * U];
    }
#pragma unroll
    for (int k = 0; k < KH; ++k) {
        const float* row = Wr + (size_t)(seg * KH + k) * COLS + u;
#pragma unroll
        for (int g = 0; g < 4; ++g) w[g][KIN + k] = row[g * U];
    }
    float bz[4];
#pragma unroll
    for (int g = 0; g < 4; ++g) bz[g] = (seg == 0) ? bias[g * U + u] : 0.0f;

    if (tid < 128) xh[tid] = 0.0f;    // zero the t=0 read buffer

    float cst = 0.0f, hprev = 0.0f;

    // L1 input: 1-step-ahead register prefetch of this thread's 8-float slice
    float4 xn0 = make_float4(0.f, 0.f, 0.f, 0.f), xn1 = xn0;
    const float4* xg4 = reinterpret_cast<const float4*>(xg);
    if constexpr (FIRST) {
        xn0 = xg4[seg * 2 + 0];
        xn1 = xg4[seg * 2 + 1];
    }
    __syncthreads();

    for (int t = 0; t < TSTEPS; ++t) {
        const float* __restrict__ xr = xh + (t & 1) * 128;
        float* __restrict__ xw       = xh + ((t + 1) & 1) * 128;

        float a0 = bz[0], a1 = bz[1], a2 = bz[2], a3 = bz[3];

        // ---- input-projection part ----
        if constexpr (FIRST) {
            const float xv[8] = {xn0.x, xn0.y, xn0.z, xn0.w,
                                 xn1.x, xn1.y, xn1.z, xn1.w};
            if (t + 1 < TSTEPS) {
                xn0 = xg4[(t + 1) * 16 + seg * 2 + 0];
                xn1 = xg4[(t + 1) * 16 + seg * 2 + 1];
            }
#pragma unroll
            for (int k = 0; k < 8; ++k) {
                a0 = fmaf(xv[k], w[0][k], a0);
                a1 = fmaf(xv[k], w[1][k], a1);
                a2 = fmaf(xv[k], w[2][k], a2);
                a3 = fmaf(xv[k], w[3][k], a3);
            }
        } else {
            const float* inp = seq + t * 128 + seg * KIN;
            if constexpr (KIN % 4 == 0) {
#pragma unroll
                for (int k4 = 0; k4 < KIN / 4; ++k4) {
                    const float4 v = reinterpret_cast<const float4*>(inp)[k4];
                    a0 = fmaf(v.x, w[0][4*k4+0], a0); a1 = fmaf(v.x, w[1][4*k4+0], a1);
                    a2 = fmaf(v.x, w[2][4*k4+0], a2); a3 = fmaf(v.x, w[3][4*k4+0], a3);
                    a0 = fmaf(v.y, w[0][4*k4+1], a0); a1 = fmaf(v.y, w[1][4*k4+1], a1);
                    a2 = fmaf(v.y, w[2][4*k4+1], a2); a3 = fmaf(v.y, w[3][4*k4+1], a3);
                    a0 = fmaf(v.z, w[0][4*k4+2], a0); a1 = fmaf(v.z, w[1][4*k4+2], a1);
                    a2 = fmaf(v.z, w[2][4*k4+2], a2); a3 = fmaf(v.z, w[3][4*k4+2], a3);
                    a0 = fmaf(v.w, w[0][4*k4+3], a0); a1 = fmaf(v.w, w[1][4*k4+3], a1);
                    a2 = fmaf(v.w, w[2][4*k4+3], a2); a3 = fmaf(v.w, w[3][4*k4+3], a3);
                }
            } else {  // KIN == 2 (layer 4)
                const float2 v = *reinterpret_cast<const float2*>(inp);
                a0 = fmaf(v.x, w[0][0], a0); a1 = fmaf(v.x, w[1][0], a1);
                a2 = fmaf(v.x, w[2][0], a2); a3 = fmaf(v.x, w[3][0], a3);
                a0 = fmaf(v.y, w[0][1], a0); a1 = fmaf(v.y, w[1][1], a1);
                a2 = fmaf(v.y, w[2][1], a2); a3 = fmaf(v.y, w[3][1], a3);
            }
        }

        // ---- recurrent part ----
        {
            const float* hp = xr + seg * KH;
            if constexpr (KH % 4 == 0) {
#pragma unroll
                for (int k4 = 0; k4 < KH / 4; ++k4) {
                    const float4 v = reinterpret_cast<const float4*>(hp)[k4];
                    const int kb = KIN + 4 * k4;
                    a0 = fmaf(v.x, w[0][kb+0], a0); a1 = fmaf(v.x, w[1][kb+0], a1);
                    a2 = fmaf(v.x, w[2][kb+0], a2); a3 = fmaf(v.x, w[3][kb+0], a3);
                    a0 = fmaf(v.y, w[0][kb+1], a0); a1 = fmaf(v.y, w[1][kb+1], a1);
                    a2 = fmaf(v.y, w[2][kb+1], a2); a3 = fmaf(v.y, w[3][kb+1], a3);
                    a0 = fmaf(v.z, w[0][kb+2], a0); a1 = fmaf(v.z, w[1][kb+2], a1);
                    a2 = fmaf(v.z, w[2][kb+2], a2); a3 = fmaf(v.z, w[3][kb+2], a3);
                    a0 = fmaf(v.w, w[0][kb+3], a0); a1 = fmaf(v.w, w[1][kb+3], a1);
                    a2 = fmaf(v.w, w[2][kb+3], a2); a3 = fmaf(v.w, w[3][kb+3], a3);
                }
            } else {  // KH == 1 (layer 4)
                const float v = hp[0];
                a0 = fmaf(v, w[0][KIN], a0); a1 = fmaf(v, w[1][KIN], a1);
                a2 = fmaf(v, w[2][KIN], a2); a3 = fmaf(v, w[3][KIN], a3);
            }
        }

        // ---- in-wave reduction over segs: all lanes get the full sums ----
        a0 = allreduce_seg<NS>(a0);
        a1 = allreduce_seg<NS>(a1);
        a2 = allreduce_seg<NS>(a2);
        a3 = allreduce_seg<NS>(a3);

        if constexpr (WRITE_DELAY) {
            if (seg == 0 && t > 0) seq[(t - 1) * 128 + u] = hprev;
        }

        // ---- gate update (redundant across seg lanes, bitwise identical) ----
        const float gi = sigmoidf_(a0);
        const float gf = sigmoidf_(a1);
        const float gg = fmaxf(a2, 0.0f);          // cell activation = relu
        const float go = sigmoidf_(a3);
        cst = fmaf(gf, cst, gi * gg);
        const float h = go * fmaxf(cst, 0.0f);     // output activation = relu

        if (seg == 0) {
            xw[u] = h;
            if constexpr (WRITE_NOW) seq[t * 128 + u] = h;
        }
        hprev = h;
        __syncthreads();
    }

    if constexpr (WRITE_DELAY) {
        if (seg == 0) seq[(TSTEPS - 1) * 128 + u] = hprev;
    }
}

extern "C" __global__ void __launch_bounds__(NTHREADS, 4)
lstm_stack_kernel(const float* __restrict__ x,
                  const float* __restrict__ W1, const float* __restrict__ U1, const float* __restrict__ b1,
                  const float* __restrict__ W2, const float* __restrict__ U2, const float* __restrict__ b2,
                  const float* __restrict__ W3, const float* __restrict__ U3, const float* __restrict__ b3,
                  const float* __restrict__ W4, const float* __restrict__ U4, const float* __restrict__ b4,
                  const float* __restrict__ Wf, const float* __restrict__ bf,
                  const float* __restrict__ Wo, const float* __restrict__ bo,
                  float* __restrict__ out)
{
    __shared__ __align__(16) float seq[TSTEPS * 128];   // 147456 B
    __shared__ __align__(16) float xh[256 + 16];        // ping-pong h + head tmp

    const int tid = threadIdx.x;
    const float* xg = x + (size_t)blockIdx.x * TSTEPS * 64;

    //            DIN    U  FIRST  NOW    DELAY
    run_layer< 64, 128, true , true , false>(W1, U1, b1, xg, seq, xh, tid);
    __syncthreads();
    run_layer<128,  64, false, false, true >(W2, U2, b2, xg, seq, xh, tid);
    __syncthreads();
    run_layer< 64,  64, false, false, true >(W3, U3, b3, xg, seq, xh, tid);
    __syncthreads();
    run_layer< 64,  32, false, false, false>(W4, U4, b4, xg, seq, xh, tid);
    __syncthreads();

    // ---- FC head: h4 final is in xh[0..32) (T even -> buffer 0) ----
    if (tid < 16) {
        float acc = bf[tid];
#pragma unroll
        for (int k = 0; k < 32; ++k) acc = fmaf(xh[k], Wf[k * 16 + tid], acc);
        xh[256 + tid] = fmaxf(acc, 0.0f);
    }
    __syncthreads();
    if (tid == 0) {
        float acc = bo[0];
#pragma unroll
        for (int k = 0; k < 16; ++k) acc = fmaf(xh[256 + k], Wo[k], acc);
        out[blockIdx.x] = acc;
    }
}

extern "C" void kernel_launch(void* const* d_in, const int* in_sizes, int n_in,
                              void* d_out, int out_size, void* d_ws, size_t ws_size,
                              hipStream_t stream) {
    const float* x  = (const float*)d_in[0];
    const float* W1 = (const float*)d_in[1];
    const float* U1 = (const float*)d_in[2];
    const float* b1 = (const float*)d_in[3];
    const float* W2 = (const float*)d_in[4];
    const float* U2 = (const float*)d_in[5];
    const float* b2 = (const float*)d_in[6];
    const float* W3 = (const float*)d_in[7];
    const float* U3 = (const float*)d_in[8];
    const float* b3 = (const float*)d_in[9];
    const float* W4 = (const float*)d_in[10];
    const float* U4 = (const float*)d_in[11];
    const float* b4 = (const float*)d_in[12];
    const float* Wf = (const float*)d_in[13];
    const float* bf = (const float*)d_in[14];
    const float* Wo = (const float*)d_in[15];
    const float* bo = (const float*)d_in[16];
    float* out = (float*)d_out;

    lstm_stack_kernel<<<dim3(256), dim3(NTHREADS), 0, stream>>>(
        x, W1, U1, b1, W2, U2, b2, W3, U3, b3, W4, U4, b4, Wf, bf, Wo, bo, out);
}

// Round 4
// 787.898 us; speedup vs baseline: 1.2252x; 1.2252x over previous
//
#include <hip/hip_runtime.h>
#include <math.h>

#define TSTEPS 288
#define NTHREADS 1024

__device__ __forceinline__ float sigmoidf_(float x) {
    return 1.0f / (1.0f + __expf(-x));
}

// Butterfly all-reduce over lane bits 0..2 (NS=8). xor1/xor2 via DPP
// quad_perm (VALU pipe), xor4 via ds_swizzle. All 8 lanes of a seg-group end
// with the bitwise-identical sum.
__device__ __forceinline__ float allreduce8(float v) {
    v += __int_as_float(__builtin_amdgcn_update_dpp(
            0, __float_as_int(v), 0xB1, 0xF, 0xF, true));   // quad_perm xor 1
    v += __int_as_float(__builtin_amdgcn_update_dpp(
            0, __float_as_int(v), 0x4E, 0xF, 0xF, true));   // quad_perm xor 2
    v += __int_as_float(__builtin_amdgcn_ds_swizzle(
            __float_as_int(v), 0x101F));                    // xor 4
    return v;
}

// One block = one sample. Thread (u, seg): u = tid>>3 owns unit u's 4 gate
// columns {u, U+u, 2U+u, 3U+u}; seg = tid&7 covers KIN input + KH hidden rows.
// Cross-seg reduce = in-wave butterfly; gate update redundant across the 8
// seg lanes (bitwise identical). One barrier per timestep, xh ping-pong.
// ACTIVE threads participate; waves >= ACTIVE only execute the barrier loop.
template<int DIN, int U, int ACTIVE, bool FIRST, bool WRITE_NOW, bool WRITE_DELAY>
__device__ void run_layer(const float* __restrict__ Wk,
                          const float* __restrict__ Wr,
                          const float* __restrict__ bias,
                          const float* __restrict__ xg,   // x + b*T*64 (FIRST only)
                          float* __restrict__ seq,
                          float* __restrict__ xh,         // 2 x 128 ping-pong
                          int tid)
{
    constexpr int NS  = 8;
    constexpr int KIN = DIN / NS;
    constexpr int KH  = U / NS;
    constexpr int KT  = KIN + KH;
    constexpr int COLS = 4 * U;
    static_assert(ACTIVE == NS * U, "thread mapping");
    static_assert(KIN % 4 == 0 && KH % 4 == 0, "float4 alignment");

    const int seg = tid & 7;
    const int u   = tid >> 3;
    const bool act = tid < ACTIVE;

    float w[4][KT];
    float bz[4] = {0.f, 0.f, 0.f, 0.f};
    float cst = 0.0f, hprev = 0.0f;
    float4 xn0 = make_float4(0.f,0.f,0.f,0.f), xn1 = xn0;
    const float4* xg4 = reinterpret_cast<const float4*>(xg);

    if (act) {
        // ---- register-resident weights: 4 gate columns x KT rows ----
#pragma unroll
        for (int k = 0; k < KIN; ++k) {
            const float* row = Wk + (size_t)(seg * KIN + k) * COLS + u;
#pragma unroll
            for (int g = 0; g < 4; ++g) w[g][k] = row[g * U];
        }
#pragma unroll
        for (int k = 0; k < KH; ++k) {
            const float* row = Wr + (size_t)(seg * KH + k) * COLS + u;
#pragma unroll
            for (int g = 0; g < 4; ++g) w[g][KIN + k] = row[g * U];
        }
        if (seg == 0) {
#pragma unroll
            for (int g = 0; g < 4; ++g) bz[g] = bias[g * U + u];
        }
        // Pin every weight in a VGPR: the empty asm makes each value opaque,
        // so the allocator can neither sink nor rematerialize the loads
        // inside the t-loop (the R3 failure mode).
#pragma unroll
        for (int g = 0; g < 4; ++g)
#pragma unroll
            for (int k = 0; k < KT; ++k)
                asm volatile("" : "+v"(w[g][k]));
        if constexpr (FIRST) {
            xn0 = xg4[seg * 2 + 0];
            xn1 = xg4[seg * 2 + 1];
        }
    }
    if (tid < 128) xh[tid] = 0.0f;     // zero the t=0 read buffer
    __syncthreads();

    for (int t = 0; t < TSTEPS; ++t) {
        if (act) {
            const float* __restrict__ xr = xh + (t & 1) * 128;
            float* __restrict__ xw       = xh + ((t + 1) & 1) * 128;

            float a0 = bz[0], a1 = bz[1], a2 = bz[2], a3 = bz[3];

            // ---- input-projection part ----
            if constexpr (FIRST) {
                const float4 c0 = xn0, c1 = xn1;
                if (t + 1 < TSTEPS) {
                    xn0 = xg4[(t + 1) * 16 + seg * 2 + 0];
                    xn1 = xg4[(t + 1) * 16 + seg * 2 + 1];
                }
                const float xv[8] = {c0.x, c0.y, c0.z, c0.w, c1.x, c1.y, c1.z, c1.w};
#pragma unroll
                for (int k = 0; k < 8; ++k) {
                    a0 = fmaf(xv[k], w[0][k], a0);
                    a1 = fmaf(xv[k], w[1][k], a1);
                    a2 = fmaf(xv[k], w[2][k], a2);
                    a3 = fmaf(xv[k], w[3][k], a3);
                }
            } else {
                const float4* in4 = reinterpret_cast<const float4*>(seq + t * 128 + seg * KIN);
#pragma unroll
                for (int k4 = 0; k4 < KIN / 4; ++k4) {
                    const float4 v = in4[k4];
                    a0 = fmaf(v.x, w[0][4*k4+0], a0); a1 = fmaf(v.x, w[1][4*k4+0], a1);
                    a2 = fmaf(v.x, w[2][4*k4+0], a2); a3 = fmaf(v.x, w[3][4*k4+0], a3);
                    a0 = fmaf(v.y, w[0][4*k4+1], a0); a1 = fmaf(v.y, w[1][4*k4+1], a1);
                    a2 = fmaf(v.y, w[2][4*k4+1], a2); a3 = fmaf(v.y, w[3][4*k4+1], a3);
                    a0 = fmaf(v.z, w[0][4*k4+2], a0); a1 = fmaf(v.z, w[1][4*k4+2], a1);
                    a2 = fmaf(v.z, w[2][4*k4+2], a2); a3 = fmaf(v.z, w[3][4*k4+2], a3);
                    a0 = fmaf(v.w, w[0][4*k4+3], a0); a1 = fmaf(v.w, w[1][4*k4+3], a1);
                    a2 = fmaf(v.w, w[2][4*k4+3], a2); a3 = fmaf(v.w, w[3][4*k4+3], a3);
                }
            }

            // ---- recurrent part ----
            {
                const float4* h4 = reinterpret_cast<const float4*>(xr + seg * KH);
#pragma unroll
                for (int k4 = 0; k4 < KH / 4; ++k4) {
                    const float4 v = h4[k4];
                    const int kb = KIN + 4 * k4;
                    a0 = fmaf(v.x, w[0][kb+0], a0); a1 = fmaf(v.x, w[1][kb+0], a1);
                    a2 = fmaf(v.x, w[2][kb+0], a2); a3 = fmaf(v.x, w[3][kb+0], a3);
                    a0 = fmaf(v.y, w[0][kb+1], a0); a1 = fmaf(v.y, w[1][kb+1], a1);
                    a2 = fmaf(v.y, w[2][kb+1], a2); a3 = fmaf(v.y, w[3][kb+1], a3);
                    a0 = fmaf(v.z, w[0][kb+2], a0); a1 = fmaf(v.z, w[1][kb+2], a1);
                    a2 = fmaf(v.z, w[2][kb+2], a2); a3 = fmaf(v.z, w[3][kb+2], a3);
                    a0 = fmaf(v.w, w[0][kb+3], a0); a1 = fmaf(v.w, w[1][kb+3], a1);
                    a2 = fmaf(v.w, w[2][kb+3], a2); a3 = fmaf(v.w, w[3][kb+3], a3);
                }
            }

            // ---- in-wave reduction: all 8 seg lanes get the full sums ----
            a0 = allreduce8(a0);
            a1 = allreduce8(a1);
            a2 = allreduce8(a2);
            a3 = allreduce8(a3);

            if constexpr (WRITE_DELAY) {
                if (seg == 0 && t > 0) seq[(t - 1) * 128 + u] = hprev;
            }

            // ---- gate update (redundant across seg lanes) ----
            const float gi = sigmoidf_(a0);
            const float gf = sigmoidf_(a1);
            const float gg = fmaxf(a2, 0.0f);          // cell activation = relu
            const float go = sigmoidf_(a3);
            cst = fmaf(gf, cst, gi * gg);
            const float h = go * fmaxf(cst, 0.0f);     // output activation = relu

            if (seg == 0) {
                xw[u] = h;
                if constexpr (WRITE_NOW) seq[t * 128 + u] = h;
            }
            hprev = h;
        }
        __syncthreads();
    }

    if constexpr (WRITE_DELAY) {
        if (act && seg == 0) seq[(TSTEPS - 1) * 128 + u] = hprev;
    }
}

extern "C" __global__ void
__attribute__((amdgpu_flat_work_group_size(NTHREADS, NTHREADS), amdgpu_waves_per_eu(4, 4)))
lstm_stack_kernel(const float* __restrict__ x,
                  const float* __restrict__ W1, const float* __restrict__ U1, const float* __restrict__ b1,
                  const float* __restrict__ W2, const float* __restrict__ U2, const float* __restrict__ b2,
                  const float* __restrict__ W3, const float* __restrict__ U3, const float* __restrict__ b3,
                  const float* __restrict__ W4, const float* __restrict__ U4, const float* __restrict__ b4,
                  const float* __restrict__ Wf, const float* __restrict__ bf,
                  const float* __restrict__ Wo, const float* __restrict__ bo,
                  float* __restrict__ out)
{
    __shared__ __align__(16) float seq[TSTEPS * 128];   // 147456 B
    __shared__ __align__(16) float xh[256 + 16];        // ping-pong h + head tmp

    const int tid = threadIdx.x;
    const float* xg = x + (size_t)blockIdx.x * TSTEPS * 64;

    //            DIN    U  ACTIVE FIRST  NOW    DELAY
    run_layer< 64, 128, 1024, true , true , false>(W1, U1, b1, xg, seq, xh, tid);
    __syncthreads();
    run_layer<128,  64,  512, false, false, true >(W2, U2, b2, xg, seq, xh, tid);
    __syncthreads();
    run_layer< 64,  64,  512, false, false, true >(W3, U3, b3, xg, seq, xh, tid);
    __syncthreads();
    run_layer< 64,  32,  256, false, false, false>(W4, U4, b4, xg, seq, xh, tid);
    __syncthreads();

    // ---- FC head: h4 final is in xh[0..32) (T even -> buffer 0) ----
    if (tid < 16) {
        float acc = bf[tid];
#pragma unroll
        for (int k = 0; k < 32; ++k) acc = fmaf(xh[k], Wf[k * 16 + tid], acc);
        xh[256 + tid] = fmaxf(acc, 0.0f);
    }
    __syncthreads();
    if (tid == 0) {
        float acc = bo[0];
#pragma unroll
        for (int k = 0; k < 16; ++k) acc = fmaf(xh[256 + k], Wo[k], acc);
        out[blockIdx.x] = acc;
    }
}

extern "C" void kernel_launch(void* const* d_in, const int* in_sizes, int n_in,
                              void* d_out, int out_size, void* d_ws, size_t ws_size,
                              hipStream_t stream) {
    const float* x  = (const float*)d_in[0];
    const float* W1 = (const float*)d_in[1];
    const float* U1 = (const float*)d_in[2];
    const float* b1 = (const float*)d_in[3];
    const float* W2 = (const float*)d_in[4];
    const float* U2 = (const float*)d_in[5];
    const float* b2 = (const float*)d_in[6];
    const float* W3 = (const float*)d_in[7];
    const float* U3 = (const float*)d_in[8];
    const float* b3 = (const float*)d_in[9];
    const float* W4 = (const float*)d_in[10];
    const float* U4 = (const float*)d_in[11];
    const float* b4 = (const float*)d_in[12];
    const float* Wf = (const float*)d_in[13];
    const float* bf = (const float*)d_in[14];
    const float* Wo = (const float*)d_in[15];
    const float* bo = (const float*)d_in[16];
    float* out = (float*)d_out;

    lstm_stack_kernel<<<dim3(256), dim3(NTHREADS), 0, stream>>>(
        x, W1, U1, b1, W2, U2, b2, W3, U3, b3, W4, U4, b4, Wf, bf, Wo, bo, out);
}

// Round 5
// 699.255 us; speedup vs baseline: 1.3805x; 1.1268x over previous
//
#include <hip/hip_runtime.h>
#include <math.h>

#define TSTEPS 288
#define NTHREADS 512

__device__ __forceinline__ float sigmoidf_(float x) {
    return 1.0f / (1.0f + __expf(-x));
}

// Butterfly all-reduce over the low log2(NS) lane bits.
// xor1/xor2 via DPP quad_perm (pure VALU); xor4 via ds_swizzle.
// All NS lanes of a group end with the bitwise-identical sum.
template<int NS>
__device__ __forceinline__ float allreduce_seg(float v) {
    if constexpr (NS > 1)
        v += __int_as_float(__builtin_amdgcn_update_dpp(
                0, __float_as_int(v), 0xB1, 0xF, 0xF, true));   // quad_perm xor 1
    if constexpr (NS > 2)
        v += __int_as_float(__builtin_amdgcn_update_dpp(
                0, __float_as_int(v), 0x4E, 0xF, 0xF, true));   // quad_perm xor 2
    if constexpr (NS > 4)
        v += __int_as_float(__builtin_amdgcn_ds_swizzle(
                __float_as_int(v), 0x101F));                    // xor 4
    return v;
}

// One block = one sample. Thread (u, seg): u = tid/NS owns unit u's 4 gate
// columns {u, U+u, 2U+u, 3U+u}; seg = tid%NS covers KIN input + KH hidden
// rows. Cross-seg reduce = in-wave butterfly; gate update redundant across
// seg lanes (bitwise identical). One barrier per timestep, xh ping-pong.
// FIRST: input comes from the xring LDS double-row staged by threads 0..63.
// WRITE_NOW / WRITE_DELAY as before (WAR-safe in-place seq overwrite).
template<int DIN, int U, int NS, int ACTIVE, bool FIRST, bool WRITE_NOW, bool WRITE_DELAY>
__device__ void run_layer(const float* __restrict__ Wk,
                          const float* __restrict__ Wr,
                          const float* __restrict__ bias,
                          const float* __restrict__ xg,   // x + b*T*64 (FIRST only)
                          float* __restrict__ seq,
                          float* __restrict__ xh,         // 2 x 128 ping-pong
                          float* __restrict__ xring,      // 2 x 64 input ring
                          int tid)
{
    constexpr int KIN  = DIN / NS;
    constexpr int KH   = U / NS;
    constexpr int KT   = KIN + KH;
    constexpr int COLS = 4 * U;
    constexpr int S    = (NS == 4) ? 2 : 3;
    static_assert(ACTIVE == NS * U, "thread mapping");
    static_assert(KIN % 4 == 0 && KH % 4 == 0, "float4 alignment");
    static_assert(NS <= 8, "butterfly width");

    const int seg = tid & (NS - 1);
    const int u   = tid >> S;
    const bool act = tid < ACTIVE;

    float w[4][KT];
    float bz[4] = {0.f, 0.f, 0.f, 0.f};
    float cst = 0.0f, hprev = 0.0f;

    if (act) {
        // ---- register-resident weights: 4 gate columns x KT rows ----
#pragma unroll
        for (int k = 0; k < KIN; ++k) {
            const float* row = Wk + (size_t)(seg * KIN + k) * COLS + u;
#pragma unroll
            for (int g = 0; g < 4; ++g) w[g][k] = row[g * U];
        }
#pragma unroll
        for (int k = 0; k < KH; ++k) {
            const float* row = Wr + (size_t)(seg * KH + k) * COLS + u;
#pragma unroll
            for (int g = 0; g < 4; ++g) w[g][KIN + k] = row[g * U];
        }
        if (seg == 0) {
#pragma unroll
            for (int g = 0; g < 4; ++g) bz[g] = bias[g * U + u];
        }
        // Pin weights in VGPRs (defeats load-sinking/remat).
#pragma unroll
        for (int g = 0; g < 4; ++g)
#pragma unroll
            for (int k = 0; k < KT; ++k)
                asm volatile("" : "+v"(w[g][k]));
    }
    if (tid < 128) xh[tid] = 0.0f;                 // zero t=0 read buffer
    if (FIRST && tid < 64) xring[tid] = xg[tid];   // stage x row 0
    __syncthreads();

    for (int t = 0; t < TSTEPS; ++t) {
        if (act) {
            const float* __restrict__ xr = xh + (t & 1) * 128;
            float* __restrict__ xw       = xh + ((t + 1) & 1) * 128;

            // L1 input staging: 64 threads fetch row t+1 (coalesced 256B).
            float xstage = 0.0f;
            if (FIRST && tid < 64 && (t + 1) < TSTEPS)
                xstage = xg[(t + 1) * 64 + tid];

            float a0 = bz[0], a1 = bz[1], a2 = bz[2], a3 = bz[3];

            // ---- input-projection part ----
            {
                const float* inp = FIRST ? (xring + (t & 1) * 64 + seg * KIN)
                                         : (seq + t * 128 + seg * KIN);
                const float4* in4 = reinterpret_cast<const float4*>(inp);
#pragma unroll
                for (int k4 = 0; k4 < KIN / 4; ++k4) {
                    const float4 v = in4[k4];
                    a0 = fmaf(v.x, w[0][4*k4+0], a0); a1 = fmaf(v.x, w[1][4*k4+0], a1);
                    a2 = fmaf(v.x, w[2][4*k4+0], a2); a3 = fmaf(v.x, w[3][4*k4+0], a3);
                    a0 = fmaf(v.y, w[0][4*k4+1], a0); a1 = fmaf(v.y, w[1][4*k4+1], a1);
                    a2 = fmaf(v.y, w[2][4*k4+1], a2); a3 = fmaf(v.y, w[3][4*k4+1], a3);
                    a0 = fmaf(v.z, w[0][4*k4+2], a0); a1 = fmaf(v.z, w[1][4*k4+2], a1);
                    a2 = fmaf(v.z, w[2][4*k4+2], a2); a3 = fmaf(v.z, w[3][4*k4+2], a3);
                    a0 = fmaf(v.w, w[0][4*k4+3], a0); a1 = fmaf(v.w, w[1][4*k4+3], a1);
                    a2 = fmaf(v.w, w[2][4*k4+3], a2); a3 = fmaf(v.w, w[3][4*k4+3], a3);
                }
            }

            // ---- recurrent part ----
            {
                const float4* h4 = reinterpret_cast<const float4*>(xr + seg * KH);
#pragma unroll
                for (int k4 = 0; k4 < KH / 4; ++k4) {
                    const float4 v = h4[k4];
                    const int kb = KIN + 4 * k4;
                    a0 = fmaf(v.x, w[0][kb+0], a0); a1 = fmaf(v.x, w[1][kb+0], a1);
                    a2 = fmaf(v.x, w[2][kb+0], a2); a3 = fmaf(v.x, w[3][kb+0], a3);
                    a0 = fmaf(v.y, w[0][kb+1], a0); a1 = fmaf(v.y, w[1][kb+1], a1);
                    a2 = fmaf(v.y, w[2][kb+1], a2); a3 = fmaf(v.y, w[3][kb+1], a3);
                    a0 = fmaf(v.z, w[0][kb+2], a0); a1 = fmaf(v.z, w[1][kb+2], a1);
                    a2 = fmaf(v.z, w[2][kb+2], a2); a3 = fmaf(v.z, w[3][kb+2], a3);
                    a0 = fmaf(v.w, w[0][kb+3], a0); a1 = fmaf(v.w, w[1][kb+3], a1);
                    a2 = fmaf(v.w, w[2][kb+3], a2); a3 = fmaf(v.w, w[3][kb+3], a3);
                }
            }

            // ---- in-wave reduction: all NS seg lanes get the full sums ----
            a0 = allreduce_seg<NS>(a0);
            a1 = allreduce_seg<NS>(a1);
            a2 = allreduce_seg<NS>(a2);
            a3 = allreduce_seg<NS>(a3);

            if constexpr (WRITE_DELAY) {
                if (seg == 0 && t > 0) seq[(t - 1) * 128 + u] = hprev;
            }

            // ---- gate update (redundant across seg lanes) ----
            const float gi = sigmoidf_(a0);
            const float gf = sigmoidf_(a1);
            const float gg = fmaxf(a2, 0.0f);          // cell activation = relu
            const float go = sigmoidf_(a3);
            cst = fmaf(gf, cst, gi * gg);
            const float h = go * fmaxf(cst, 0.0f);     // output activation = relu

            if (seg == 0) {
                xw[u] = h;
                if constexpr (WRITE_NOW) seq[t * 128 + u] = h;
            }
            hprev = h;

            if (FIRST && tid < 64 && (t + 1) < TSTEPS)
                xring[((t + 1) & 1) * 64 + tid] = xstage;
        }
        __syncthreads();
    }

    if constexpr (WRITE_DELAY) {
        if (act && seg == 0) seq[(TSTEPS - 1) * 128 + u] = hprev;
    }
}

extern "C" __global__ void __launch_bounds__(NTHREADS, 2)
lstm_stack_kernel(const float* __restrict__ x,
                  const float* __restrict__ W1, const float* __restrict__ U1, const float* __restrict__ b1,
                  const float* __restrict__ W2, const float* __restrict__ U2, const float* __restrict__ b2,
                  const float* __restrict__ W3, const float* __restrict__ U3, const float* __restrict__ b3,
                  const float* __restrict__ W4, const float* __restrict__ U4, const float* __restrict__ b4,
                  const float* __restrict__ Wf, const float* __restrict__ bf,
                  const float* __restrict__ Wo, const float* __restrict__ bo,
                  float* __restrict__ out)
{
    __shared__ __align__(16) float seq[TSTEPS * 128];   // 147456 B
    __shared__ __align__(16) float xh[256 + 16];        // ping-pong h + head tmp
    __shared__ __align__(16) float xring[2 * 64];       // L1 input ring

    const int tid = threadIdx.x;
    const float* xg = x + (size_t)blockIdx.x * TSTEPS * 64;

    //            DIN    U NS ACTIVE FIRST  NOW    DELAY
    run_layer< 64, 128, 4, 512, true , true , false>(W1, U1, b1, xg, seq, xh, xring, tid);
    __syncthreads();
    run_layer<128,  64, 8, 512, false, false, true >(W2, U2, b2, xg, seq, xh, xring, tid);
    __syncthreads();
    run_layer< 64,  64, 8, 512, false, false, true >(W3, U3, b3, xg, seq, xh, xring, tid);
    __syncthreads();
    run_layer< 64,  32, 8, 256, false, false, false>(W4, U4, b4, xg, seq, xh, xring, tid);
    __syncthreads();

    // ---- FC head: h4 final is in xh[0..32) (T even -> buffer 0) ----
    if (tid < 16) {
        float acc = bf[tid];
#pragma unroll
        for (int k = 0; k < 32; ++k) acc = fmaf(xh[k], Wf[k * 16 + tid], acc);
        xh[256 + tid] = fmaxf(acc, 0.0f);
    }
    __syncthreads();
    if (tid == 0) {
        float acc = bo[0];
#pragma unroll
        for (int k = 0; k < 16; ++k) acc = fmaf(xh[256 + k], Wo[k], acc);
        out[blockIdx.x] = acc;
    }
}

extern "C" void kernel_launch(void* const* d_in, const int* in_sizes, int n_in,
                              void* d_out, int out_size, void* d_ws, size_t ws_size,
                              hipStream_t stream) {
    const float* x  = (const float*)d_in[0];
    const float* W1 = (const float*)d_in[1];
    const float* U1 = (const float*)d_in[2];
    const float* b1 = (const float*)d_in[3];
    const float* W2 = (const float*)d_in[4];
    const float* U2 = (const float*)d_in[5];
    const float* b2 = (const float*)d_in[6];
    const float* W3 = (const float*)d_in[7];
    const float* U3 = (const float*)d_in[8];
    const float* b3 = (const float*)d_in[9];
    const float* W4 = (const float*)d_in[10];
    const float* U4 = (const float*)d_in[11];
    const float* b4 = (const float*)d_in[12];
    const float* Wf = (const float*)d_in[13];
    const float* bf = (const float*)d_in[14];
    const float* Wo = (const float*)d_in[15];
    const float* bo = (const float*)d_in[16];
    float* out = (float*)d_out;

    lstm_stack_kernel<<<dim3(256), dim3(NTHREADS), 0, stream>>>(
        x, W1, U1, b1, W2, U2, b2, W3, U3, b3, W4, U4, b4, Wf, bf, Wo, bo, out);
}